// Round 12
// baseline (175.265 us; speedup 1.0000x reference)
//
#include <hip/hip_runtime.h>
#include <hip/hip_bf16.h>
#include <math.h>

typedef unsigned short ushort_t;
typedef __attribute__((ext_vector_type(8))) short short8;
typedef __attribute__((ext_vector_type(4))) float float4v;

#define NN 4096
#define BB 4
#define CC 64
#define ICH 32

#define OFF_QB 0
#define OFF_KB 262144
#define OFF_VT 524288
#define OFF_OP 786432

static __device__ __forceinline__ ushort_t f2b(float f) {
  union { float f; unsigned u; } v;
  v.f = f;
  return (ushort_t)((v.u + 0x8000u) >> 16);
}
static __device__ __forceinline__ unsigned pack2(float x, float y) {
  return (unsigned)f2b(x) | ((unsigned)f2b(y) << 16);
}
static __device__ __forceinline__ short8 cvt8lds(const float* p) {
  short8 r;
#pragma unroll
  for (int j = 0; j < 8; j++) r[j] = (short)f2b(p[j]);
  return r;
}

// ---------------------------------------------------------------------------
// Kernel 1: projections via MFMA, one projection per blockIdx.z (R11-proven).
// ---------------------------------------------------------------------------
__global__ __launch_bounds__(256) void proj_kernel(
    const float* __restrict__ xt, const float* __restrict__ xo,
    const float* __restrict__ gw, const float* __restrict__ gb,
    const float* __restrict__ tw, const float* __restrict__ tb,
    const float* __restrict__ pw, const float* __restrict__ pb,
    ushort_t* __restrict__ Qb, ushort_t* __restrict__ Kb,
    ushort_t* __restrict__ Vt) {
  __shared__ float xls[64 * 68];
  __shared__ float wls[ICH * 68];
  __shared__ float bls[ICH];
  __shared__ ushort_t ol[2304];

  int t = threadIdx.x;
  int wv = t >> 6, lane = t & 63, l15 = lane & 15, quad = lane >> 4;
  int b = blockIdx.y, z = blockIdx.z;
  int n0 = blockIdx.x * 64;

  const float* xsrc = (z == 1) ? xo : xt;
  const float* W = (z == 0) ? tw : (z == 1) ? pw : gw;
  const float* Bv = (z == 0) ? tb : (z == 1) ? pb : gb;

#pragma unroll
  for (int it = 0; it < 4; it++) {
    int lin = it * 256 + t;
    int row = lin >> 4, seg = lin & 15;
    float4 v = *(const float4*)(xsrc + ((size_t)(n0 + row) * BB + b) * CC + seg * 4);
    *(float4*)(xls + row * 68 + seg * 4) = v;
  }
#pragma unroll
  for (int it = 0; it < 2; it++) {
    int lin = it * 256 + t;
    int row = lin >> 4, seg = lin & 15;
    float4 v = *(const float4*)(W + (size_t)row * CC + seg * 4);
    *(float4*)(wls + row * 68 + seg * 4) = v;
  }
  if (t < ICH) bls[t] = Bv[t];
  __syncthreads();

  const float* xr = xls + (wv * 16 + l15) * 68;
  short8 a0 = cvt8lds(xr + quad * 8);
  short8 a1 = cvt8lds(xr + 32 + quad * 8);

#pragma unroll
  for (int h = 0; h < 2; h++) {
    int i = h * 16 + l15;
    short8 b0 = cvt8lds(wls + i * 68 + quad * 8);
    short8 b1 = cvt8lds(wls + i * 68 + 32 + quad * 8);
    float bias = bls[i];
    float4v acc = {bias, bias, bias, bias};
    acc = __builtin_amdgcn_mfma_f32_16x16x32_bf16(a0, b0, acc, 0, 0, 0);
    acc = __builtin_amdgcn_mfma_f32_16x16x32_bf16(a1, b1, acc, 0, 0, 0);
    if (z < 2) {
#pragma unroll
      for (int r = 0; r < 4; r++)
        ol[(wv * 16 + quad * 4 + r) * 36 + i] = f2b(acc[r]);
    } else {
#pragma unroll
      for (int r = 0; r < 4; r++)
        ol[i * 68 + wv * 16 + quad * 4 + r] = f2b(acc[r]);
    }
  }
  __syncthreads();

  if (z < 2) {
    ushort_t* dst = (z == 0) ? Kb : Qb;
    int row = t >> 2, seg = t & 3;
    short8 v;
#pragma unroll
    for (int k = 0; k < 8; k++) v[k] = (short)ol[row * 36 + seg * 8 + k];
    *(short8*)(dst + ((size_t)b * NN + n0 + row) * ICH + seg * 8) = v;
  } else {
    int i = t & 31, seg = t >> 5;
    short8 v;
#pragma unroll
    for (int k = 0; k < 8; k++) v[k] = (short)ol[i * 68 + seg * 8 + k];
    *(short8*)(Vt + (size_t)(b * ICH + i) * NN + n0 + seg * 8) = v;
  }
}

// ---------------------------------------------------------------------------
// Kernel 2: MFMA attention partials.  4 Q-frags/wave (64 q rows), register-
// butterfly C->A (bit-exact verified), 1-chunk K/V rotating prefetch,
// splits=16 for 4 waves/SIMD.  Unnormalized exp, additive split partials.
// ---------------------------------------------------------------------------
__global__ __launch_bounds__(256) void attn_kernel(
    const ushort_t* __restrict__ Qb, const ushort_t* __restrict__ Kb,
    const ushort_t* __restrict__ Vt, float* __restrict__ OP,
    float* __restrict__ LS, int splits) {
  int t = threadIdx.x;
  int wv = t >> 6, lane = t & 63, l15 = lane & 15, quad = lane >> 4;
  int s = blockIdx.y, b = blockIdx.z;
  int q0 = blockIdx.x * 256 + wv * 64;
  int kspan = NN / splits;

  short8 qf[4];
#pragma unroll
  for (int f = 0; f < 4; f++)
    qf[f] = *(const short8*)(Qb + ((size_t)b * NN + q0 + f * 16 + l15) * ICH +
                             quad * 8);

  float4v o[4][2];
#pragma unroll
  for (int f = 0; f < 4; f++) {
    o[f][0] = (float4v){0.f, 0.f, 0.f, 0.f};
    o[f][1] = (float4v){0.f, 0.f, 0.f, 0.f};
  }
  float lsp[4] = {0.f, 0.f, 0.f, 0.f};

  const ushort_t* Kbb = Kb + (size_t)b * NN * ICH;
  const ushort_t* Vtb = Vt + (size_t)b * ICH * NN;
  int mbeg = s * kspan, mend = mbeg + kspan;

  const bool lowq = (quad < 2);
  const bool evenq = ((quad & 1) == 0);

  // current-chunk regs, prefetched
  const ushort_t* kp = Kbb + (size_t)(mbeg + l15) * ICH + quad * 8;
  const ushort_t* vp = Vtb + (size_t)l15 * NN + mbeg + quad * 8;
  short8 kc0 = *(const short8*)(kp);
  short8 kc1 = *(const short8*)(kp + 16 * ICH);
  short8 vc0 = *(const short8*)(vp);
  short8 vc1 = *(const short8*)(vp + 16 * NN);

  for (int m0 = mbeg; m0 < mend; m0 += 32) {
    // prefetch next chunk before the dependent chain
    short8 kn0, kn1, vn0, vn1;
    if (m0 + 32 < mend) {
      const ushort_t* kpn = Kbb + (size_t)(m0 + 32 + l15) * ICH + quad * 8;
      const ushort_t* vpn = Vtb + (size_t)l15 * NN + (m0 + 32) + quad * 8;
      kn0 = *(const short8*)(kpn);
      kn1 = *(const short8*)(kpn + 16 * ICH);
      vn0 = *(const short8*)(vpn);
      vn1 = *(const short8*)(vpn + 16 * NN);
    }

#pragma unroll
    for (int f = 0; f < 4; f++) {
      float4v z = {0.f, 0.f, 0.f, 0.f};
      float4v st0 = __builtin_amdgcn_mfma_f32_16x16x32_bf16(kc0, qf[f], z, 0, 0, 0);
      float4v st1 = __builtin_amdgcn_mfma_f32_16x16x32_bf16(kc1, qf[f], z, 0, 0, 0);

      float p0[4], p1[4];
#pragma unroll
      for (int r = 0; r < 4; r++) {
        p0[r] = __expf(fminf(st0[r], 60.f));
        p1[r] = __expf(fminf(st1[r], 60.f));
        lsp[f] += p0[r] + p1[r];
      }
      unsigned d0 = pack2(p0[0], p0[1]);
      unsigned d1 = pack2(p0[2], p0[3]);
      unsigned d2 = pack2(p1[0], p1[1]);
      unsigned d3 = pack2(p1[2], p1[3]);
      unsigned e0 = lowq ? d2 : d0, e1 = lowq ? d3 : d1;
      unsigned k0 = lowq ? d0 : d2, k1 = lowq ? d1 : d3;
      unsigned r0 = (unsigned)__shfl_xor((int)e0, 32, 64);
      unsigned r1 = (unsigned)__shfl_xor((int)e1, 32, 64);
      unsigned a0 = lowq ? k0 : r0;
      unsigned a1 = lowq ? k1 : r1;
      unsigned a2 = lowq ? r0 : k0;
      unsigned a3 = lowq ? r1 : k1;
      unsigned f0 = evenq ? a2 : a0, f1 = evenq ? a3 : a1;
      unsigned g0 = evenq ? a0 : a2, g1 = evenq ? a1 : a3;
      unsigned s0w = (unsigned)__shfl_xor((int)f0, 16, 64);
      unsigned s1w = (unsigned)__shfl_xor((int)f1, 16, 64);
      unsigned w0 = evenq ? g0 : s0w;
      unsigned w1 = evenq ? g1 : s1w;
      unsigned w2 = evenq ? s0w : g0;
      unsigned w3 = evenq ? s1w : g1;

      union { unsigned u[4]; short8 s8; } pu;
      pu.u[0] = w0; pu.u[1] = w1; pu.u[2] = w2; pu.u[3] = w3;
      short8 pf = pu.s8;

      o[f][0] = __builtin_amdgcn_mfma_f32_16x16x32_bf16(pf, vc0, o[f][0], 0, 0, 0);
      o[f][1] = __builtin_amdgcn_mfma_f32_16x16x32_bf16(pf, vc1, o[f][1], 0, 0, 0);
    }
    kc0 = kn0; kc1 = kn1; vc0 = vn0; vc1 = vn1;
  }

  size_t base = (size_t)(b * splits + s) * NN;
#pragma unroll
  for (int f = 0; f < 4; f++) {
    float v = lsp[f];
    v += __shfl_xor(v, 16, 64);
    v += __shfl_xor(v, 32, 64);
    if (quad == 0) LS[base + q0 + f * 16 + l15] = v;
#pragma unroll
    for (int r = 0; r < 4; r++) {
      int q = q0 + f * 16 + quad * 4 + r;
      float* op = OP + (base + q) * ICH;
      op[l15] = o[f][0][r];
      op[16 + l15] = o[f][1][r];
    }
  }
}

// ---------------------------------------------------------------------------
// Kernel 3: combine splits + wz + BN stat partials (proven).
// ---------------------------------------------------------------------------
__global__ __launch_bounds__(256) void wz_kernel(
    const float* __restrict__ OP, const float* __restrict__ LS,
    const float* __restrict__ wz_w, const float* __restrict__ wz_b,
    float* __restrict__ WY, float* __restrict__ SP, int splits) {
  __shared__ float yl[64 * 36];
  __shared__ float lsum[64];
  __shared__ float red1[256], red2[256];

  int b = blockIdx.y, n0 = blockIdx.x * 64, t = threadIdx.x;
  int blkid = b * 64 + blockIdx.x;

  if (t < 64) {
    float ssum = 0.f;
    for (int sp = 0; sp < splits; sp++)
      ssum += LS[(size_t)(b * splits + sp) * NN + n0 + t];
    lsum[t] = ssum;
  }
  __syncthreads();
#pragma unroll
  for (int it = 0; it < 8; it++) {
    int lin = it * 256 + t;
    int i = lin & 31, dn = lin >> 5;
    float sacc = 0.f;
    for (int sp = 0; sp < splits; sp++)
      sacc += OP[((size_t)(b * splits + sp) * NN + n0 + dn) * ICH + i];
    yl[dn * 36 + i] = sacc / lsum[dn];
  }
  __syncthreads();

  int c = t >> 2, sub = t & 3;
  float4 w4[8];
#pragma unroll
  for (int j = 0; j < 8; j++) w4[j] = ((const float4*)(wz_w + c * ICH))[j];
  float bc = wz_b[c];
  float s1 = 0.f, s2 = 0.f;
#pragma unroll
  for (int d = 0; d < 16; d++) {
    int dn = sub * 16 + d;
    const float4* y4 = (const float4*)(yl + dn * 36);
    float acc = bc;
#pragma unroll
    for (int j = 0; j < 8; j++) {
      float4 y = y4[j];
      acc += w4[j].x * y.x + w4[j].y * y.y + w4[j].z * y.z + w4[j].w * y.w;
    }
    WY[((size_t)(b * CC + c)) * NN + n0 + dn] = acc;
    s1 += acc;
    s2 += acc * acc;
  }
  red1[t] = s1;
  red2[t] = s2;
  __syncthreads();
  if (t < 64) {
    float a1 = red1[t * 4] + red1[t * 4 + 1] + red1[t * 4 + 2] + red1[t * 4 + 3];
    float a2 = red2[t * 4] + red2[t * 4 + 1] + red2[t * 4 + 2] + red2[t * 4 + 3];
    SP[(size_t)blkid * 64 + t] = a1;
    SP[16384 + (size_t)blkid * 64 + t] = a2;
  }
}

// ---------------------------------------------------------------------------
// Kernel 4: normalize + residual, with final BN stats recomputed per block
// from SP (deterministic, identical order in every block; wz completed by
// stream order).  Removes the separate stats launch.
// ---------------------------------------------------------------------------
__global__ __launch_bounds__(256) void norm_kernel(
    const float* __restrict__ SP, const float* __restrict__ gamma,
    const float* __restrict__ beta, const float* __restrict__ WY,
    const float* __restrict__ xthis, float* __restrict__ out) {
  __shared__ double rd1[256], rd2[256];
  __shared__ float abr[128];
  __shared__ float xl[64 * 65];
  int b = blockIdx.y, n0 = blockIdx.x * 64, t = threadIdx.x;

  {
    int cc = t & 63, part = t >> 6;
    double d1 = 0.0, d2 = 0.0;
    for (int k = part * 64; k < part * 64 + 64; k++) {
      d1 += (double)SP[(size_t)k * 64 + cc];
      d2 += (double)SP[16384 + (size_t)k * 64 + cc];
    }
    rd1[t] = d1;
    rd2[t] = d2;
  }
#pragma unroll
  for (int it = 0; it < 16; it++) {
    int lin = it * 256 + t;
    int c = lin & 63, dn = lin >> 6;
    xl[dn * 65 + c] = xthis[((size_t)(n0 + dn) * BB + b) * CC + c];
  }
  __syncthreads();
  if (t < 64) {
    double a1 = rd1[t] + rd1[64 + t] + rd1[128 + t] + rd1[192 + t];
    double a2 = rd2[t] + rd2[64 + t] + rd2[128 + t] + rd2[192 + t];
    double inv = 1.0 / (double)(BB * NN);
    double mean = a1 * inv;
    double var = a2 * inv - mean * mean;
    if (var < 0.0) var = 0.0;
    double rstd = 1.0 / sqrt(var + 1e-5);
    float A = gamma[t] * (float)rstd;
    abr[t] = A;
    abr[64 + t] = beta[t] - (float)mean * A;
  }
  __syncthreads();
#pragma unroll
  for (int it = 0; it < 16; it++) {
    int lin = it * 256 + t;
    int c = lin >> 6, dn = lin & 63;
    size_t idx = ((size_t)(b * CC + c)) * NN + n0 + dn;
    out[idx] = WY[idx] * abr[c] + abr[64 + c] + xl[dn * 65 + c];
  }
}

// ---------------------------------------------------------------------------
extern "C" void kernel_launch(void* const* d_in, const int* in_sizes, int n_in,
                              void* d_out, int out_size, void* d_ws,
                              size_t ws_size, hipStream_t stream) {
  const float* x_this = (const float*)d_in[0];
  const float* x_other = (const float*)d_in[1];
  const float* g_w = (const float*)d_in[2];
  const float* g_b = (const float*)d_in[3];
  const float* th_w = (const float*)d_in[4];
  const float* th_b = (const float*)d_in[5];
  const float* ph_w = (const float*)d_in[6];
  const float* ph_b = (const float*)d_in[7];
  const float* wz_w = (const float*)d_in[8];
  const float* wz_b = (const float*)d_in[9];
  const float* gamma = (const float*)d_in[10];
  const float* beta = (const float*)d_in[11];
  float* out = (float*)d_out;

  float* ws = (float*)d_ws;
  ushort_t* Qb = (ushort_t*)(ws + OFF_QB);
  ushort_t* Kb = (ushort_t*)(ws + OFF_KB);
  ushort_t* Vt = (ushort_t*)(ws + OFF_VT);

  int splits = 16;
  while (splits > 1 &&
         ws_size < (size_t)(786432 + (size_t)splits * 540672 + 32768 +
                            1048576) * 4)
    splits >>= 1;
  float* OP = ws + OFF_OP;
  float* LS = OP + (size_t)splits * 524288;
  float* SP = LS + (size_t)splits * 16384;
  float* WY = SP + 32768;

  hipLaunchKernelGGL(proj_kernel, dim3(NN / 64, BB, 3), dim3(256), 0, stream,
                     x_this, x_other, g_w, g_b, th_w, th_b, ph_w, ph_b,
                     Qb, Kb, Vt);
  hipLaunchKernelGGL(attn_kernel, dim3(NN / 256, splits, BB), dim3(256), 0,
                     stream, Qb, Kb, Vt, OP, LS, splits);
  hipLaunchKernelGGL(wz_kernel, dim3(NN / 64, BB), dim3(256), 0, stream,
                     OP, LS, wz_w, wz_b, WY, SP, splits);
  hipLaunchKernelGGL(norm_kernel, dim3(NN / 64, BB), dim3(256), 0, stream,
                     SP, gamma, beta, WY, x_this, out);
}

// Round 13
// 160.066 us; speedup vs baseline: 1.0950x; 1.0950x over previous
//
#include <hip/hip_runtime.h>
#include <hip/hip_bf16.h>
#include <math.h>

typedef unsigned short ushort_t;
typedef __attribute__((ext_vector_type(8))) short short8;
typedef __attribute__((ext_vector_type(4))) float float4v;

#define NN 4096
#define BB 4
#define CC 64
#define ICH 32

#define OFF_QB 0
#define OFF_KB 262144
#define OFF_VT 524288
#define OFF_OP 786432

static __device__ __forceinline__ ushort_t f2b(float f) {
  union { float f; unsigned u; } v;
  v.f = f;
  return (ushort_t)((v.u + 0x8000u) >> 16);
}
static __device__ __forceinline__ unsigned pack2(float x, float y) {
  return (unsigned)f2b(x) | ((unsigned)f2b(y) << 16);
}
static __device__ __forceinline__ short8 cvt8lds(const float* p) {
  short8 r;
#pragma unroll
  for (int j = 0; j < 8; j++) r[j] = (short)f2b(p[j]);
  return r;
}

// ---------------------------------------------------------------------------
// Kernel 1: projections via MFMA, one projection per blockIdx.z (R11-proven).
// ---------------------------------------------------------------------------
__global__ __launch_bounds__(256) void proj_kernel(
    const float* __restrict__ xt, const float* __restrict__ xo,
    const float* __restrict__ gw, const float* __restrict__ gb,
    const float* __restrict__ tw, const float* __restrict__ tb,
    const float* __restrict__ pw, const float* __restrict__ pb,
    ushort_t* __restrict__ Qb, ushort_t* __restrict__ Kb,
    ushort_t* __restrict__ Vt) {
  __shared__ float xls[64 * 68];
  __shared__ float wls[ICH * 68];
  __shared__ float bls[ICH];
  __shared__ ushort_t ol[2304];

  int t = threadIdx.x;
  int wv = t >> 6, lane = t & 63, l15 = lane & 15, quad = lane >> 4;
  int b = blockIdx.y, z = blockIdx.z;
  int n0 = blockIdx.x * 64;

  const float* xsrc = (z == 1) ? xo : xt;
  const float* W = (z == 0) ? tw : (z == 1) ? pw : gw;
  const float* Bv = (z == 0) ? tb : (z == 1) ? pb : gb;

#pragma unroll
  for (int it = 0; it < 4; it++) {
    int lin = it * 256 + t;
    int row = lin >> 4, seg = lin & 15;
    float4 v = *(const float4*)(xsrc + ((size_t)(n0 + row) * BB + b) * CC + seg * 4);
    *(float4*)(xls + row * 68 + seg * 4) = v;
  }
#pragma unroll
  for (int it = 0; it < 2; it++) {
    int lin = it * 256 + t;
    int row = lin >> 4, seg = lin & 15;
    float4 v = *(const float4*)(W + (size_t)row * CC + seg * 4);
    *(float4*)(wls + row * 68 + seg * 4) = v;
  }
  if (t < ICH) bls[t] = Bv[t];
  __syncthreads();

  const float* xr = xls + (wv * 16 + l15) * 68;
  short8 a0 = cvt8lds(xr + quad * 8);
  short8 a1 = cvt8lds(xr + 32 + quad * 8);

#pragma unroll
  for (int h = 0; h < 2; h++) {
    int i = h * 16 + l15;
    short8 b0 = cvt8lds(wls + i * 68 + quad * 8);
    short8 b1 = cvt8lds(wls + i * 68 + 32 + quad * 8);
    float bias = bls[i];
    float4v acc = {bias, bias, bias, bias};
    acc = __builtin_amdgcn_mfma_f32_16x16x32_bf16(a0, b0, acc, 0, 0, 0);
    acc = __builtin_amdgcn_mfma_f32_16x16x32_bf16(a1, b1, acc, 0, 0, 0);
    if (z < 2) {
#pragma unroll
      for (int r = 0; r < 4; r++)
        ol[(wv * 16 + quad * 4 + r) * 36 + i] = f2b(acc[r]);
    } else {
#pragma unroll
      for (int r = 0; r < 4; r++)
        ol[i * 68 + wv * 16 + quad * 4 + r] = f2b(acc[r]);
    }
  }
  __syncthreads();

  if (z < 2) {
    ushort_t* dst = (z == 0) ? Kb : Qb;
    int row = t >> 2, seg = t & 3;
    short8 v;
#pragma unroll
    for (int k = 0; k < 8; k++) v[k] = (short)ol[row * 36 + seg * 8 + k];
    *(short8*)(dst + ((size_t)b * NN + n0 + row) * ICH + seg * 8) = v;
  } else {
    int i = t & 31, seg = t >> 5;
    short8 v;
#pragma unroll
    for (int k = 0; k < 8; k++) v[k] = (short)ol[i * 68 + seg * 8 + k];
    *(short8*)(Vt + (size_t)(b * ICH + i) * NN + n0 + seg * 8) = v;
  }
}

// ---------------------------------------------------------------------------
// Kernel 2: MFMA attention partials.  K/V chunk staged ONCE per block into
// double-buffered LDS (4KB/chunk; one coalesced 16B load/thread) and shared
// by all 4 waves -> 4x fewer VMEM instructions.  4 Q-frags/wave, register-
// butterfly C->A (bit-exact, R9-R11).  Unnormalized exp; additive splits.
// ---------------------------------------------------------------------------
__global__ __launch_bounds__(256) void attn_kernel(
    const ushort_t* __restrict__ Qb, const ushort_t* __restrict__ Kb,
    const ushort_t* __restrict__ Vt, float* __restrict__ OP,
    float* __restrict__ LS, int splits) {
  __shared__ __align__(16) ushort_t kls[2][1024];  // [buf][kr32][ch32]
  __shared__ __align__(16) ushort_t vls[2][1024];  // [buf][ch32][n32]

  int t = threadIdx.x;
  int wv = t >> 6, lane = t & 63, l15 = lane & 15, quad = lane >> 4;
  int s = blockIdx.y, b = blockIdx.z;
  int q0 = blockIdx.x * 256 + wv * 64;
  int kspan = NN / splits;
  int nch = kspan / 32;

  short8 qf[4];
#pragma unroll
  for (int f = 0; f < 4; f++)
    qf[f] = *(const short8*)(Qb + ((size_t)b * NN + q0 + f * 16 + l15) * ICH +
                             quad * 8);

  float4v o[4][2];
#pragma unroll
  for (int f = 0; f < 4; f++) {
    o[f][0] = (float4v){0.f, 0.f, 0.f, 0.f};
    o[f][1] = (float4v){0.f, 0.f, 0.f, 0.f};
  }
  float lsp[4] = {0.f, 0.f, 0.f, 0.f};

  const ushort_t* Kbb = Kb + (size_t)b * NN * ICH;
  const ushort_t* Vtb = Vt + (size_t)b * ICH * NN;
  int mbeg = s * kspan;

  const bool lowq = (quad < 2);
  const bool evenq = ((quad & 1) == 0);

  // stage chunk at m0 into buffer buf (K: 2KB contiguous; V: 32 rows x 64B)
  auto STAGE = [&](int buf, int m0) {
    if (t < 128) {
      *(short8*)(kls[buf] + t * 8) =
          *(const short8*)(Kbb + (size_t)m0 * ICH + t * 8);
    } else {
      int u = t - 128;
      int ch = u >> 2, seg = u & 3;
      *(short8*)(vls[buf] + ch * 32 + seg * 8) =
          *(const short8*)(Vtb + (size_t)ch * NN + m0 + seg * 8);
    }
  };

  STAGE(0, mbeg);
  __syncthreads();

  for (int c = 0; c < nch; c++) {
    int cur = c & 1;
    if (c + 1 < nch) STAGE(cur ^ 1, mbeg + (c + 1) * 32);

    short8 kf0 = *(const short8*)(kls[cur] + l15 * 32 + quad * 8);
    short8 kf1 = *(const short8*)(kls[cur] + (16 + l15) * 32 + quad * 8);
    short8 vf0 = *(const short8*)(vls[cur] + l15 * 32 + quad * 8);
    short8 vf1 = *(const short8*)(vls[cur] + (16 + l15) * 32 + quad * 8);

#pragma unroll
    for (int f = 0; f < 4; f++) {
      float4v z = {0.f, 0.f, 0.f, 0.f};
      float4v st0 = __builtin_amdgcn_mfma_f32_16x16x32_bf16(kf0, qf[f], z, 0, 0, 0);
      float4v st1 = __builtin_amdgcn_mfma_f32_16x16x32_bf16(kf1, qf[f], z, 0, 0, 0);

      float p0[4], p1[4];
#pragma unroll
      for (int r = 0; r < 4; r++) {
        p0[r] = __expf(fminf(st0[r], 60.f));
        p1[r] = __expf(fminf(st1[r], 60.f));
        lsp[f] += p0[r] + p1[r];
      }
      unsigned d0 = pack2(p0[0], p0[1]);
      unsigned d1 = pack2(p0[2], p0[3]);
      unsigned d2 = pack2(p1[0], p1[1]);
      unsigned d3 = pack2(p1[2], p1[3]);
      unsigned e0 = lowq ? d2 : d0, e1 = lowq ? d3 : d1;
      unsigned k0 = lowq ? d0 : d2, k1 = lowq ? d1 : d3;
      unsigned r0 = (unsigned)__shfl_xor((int)e0, 32, 64);
      unsigned r1 = (unsigned)__shfl_xor((int)e1, 32, 64);
      unsigned a0 = lowq ? k0 : r0;
      unsigned a1 = lowq ? k1 : r1;
      unsigned a2 = lowq ? r0 : k0;
      unsigned a3 = lowq ? r1 : k1;
      unsigned f0 = evenq ? a2 : a0, f1 = evenq ? a3 : a1;
      unsigned g0 = evenq ? a0 : a2, g1 = evenq ? a1 : a3;
      unsigned s0w = (unsigned)__shfl_xor((int)f0, 16, 64);
      unsigned s1w = (unsigned)__shfl_xor((int)f1, 16, 64);
      unsigned w0 = evenq ? g0 : s0w;
      unsigned w1 = evenq ? g1 : s1w;
      unsigned w2 = evenq ? s0w : g0;
      unsigned w3 = evenq ? s1w : g1;

      union { unsigned u[4]; short8 s8; } pu;
      pu.u[0] = w0; pu.u[1] = w1; pu.u[2] = w2; pu.u[3] = w3;
      short8 pf = pu.s8;

      o[f][0] = __builtin_amdgcn_mfma_f32_16x16x32_bf16(pf, vf0, o[f][0], 0, 0, 0);
      o[f][1] = __builtin_amdgcn_mfma_f32_16x16x32_bf16(pf, vf1, o[f][1], 0, 0, 0);
    }
    __syncthreads();
  }

  size_t base = (size_t)(b * splits + s) * NN;
#pragma unroll
  for (int f = 0; f < 4; f++) {
    float v = lsp[f];
    v += __shfl_xor(v, 16, 64);
    v += __shfl_xor(v, 32, 64);
    if (quad == 0) LS[base + q0 + f * 16 + l15] = v;
#pragma unroll
    for (int r = 0; r < 4; r++) {
      int q = q0 + f * 16 + quad * 4 + r;
      float* op = OP + (base + q) * ICH;
      op[l15] = o[f][0][r];
      op[16 + l15] = o[f][1][r];
    }
  }
}

// ---------------------------------------------------------------------------
// Kernel 3: combine splits + wz + BN stat partials (proven).
// ---------------------------------------------------------------------------
__global__ __launch_bounds__(256) void wz_kernel(
    const float* __restrict__ OP, const float* __restrict__ LS,
    const float* __restrict__ wz_w, const float* __restrict__ wz_b,
    float* __restrict__ WY, float* __restrict__ SP, int splits) {
  __shared__ float yl[64 * 36];
  __shared__ float lsum[64];
  __shared__ float red1[256], red2[256];

  int b = blockIdx.y, n0 = blockIdx.x * 64, t = threadIdx.x;
  int blkid = b * 64 + blockIdx.x;

  if (t < 64) {
    float ssum = 0.f;
    for (int sp = 0; sp < splits; sp++)
      ssum += LS[(size_t)(b * splits + sp) * NN + n0 + t];
    lsum[t] = ssum;
  }
  __syncthreads();
#pragma unroll
  for (int it = 0; it < 8; it++) {
    int lin = it * 256 + t;
    int i = lin & 31, dn = lin >> 5;
    float sacc = 0.f;
    for (int sp = 0; sp < splits; sp++)
      sacc += OP[((size_t)(b * splits + sp) * NN + n0 + dn) * ICH + i];
    yl[dn * 36 + i] = sacc / lsum[dn];
  }
  __syncthreads();

  int c = t >> 2, sub = t & 3;
  float4 w4[8];
#pragma unroll
  for (int j = 0; j < 8; j++) w4[j] = ((const float4*)(wz_w + c * ICH))[j];
  float bc = wz_b[c];
  float s1 = 0.f, s2 = 0.f;
#pragma unroll
  for (int d = 0; d < 16; d++) {
    int dn = sub * 16 + d;
    const float4* y4 = (const float4*)(yl + dn * 36);
    float acc = bc;
#pragma unroll
    for (int j = 0; j < 8; j++) {
      float4 y = y4[j];
      acc += w4[j].x * y.x + w4[j].y * y.y + w4[j].z * y.z + w4[j].w * y.w;
    }
    WY[((size_t)(b * CC + c)) * NN + n0 + dn] = acc;
    s1 += acc;
    s2 += acc * acc;
  }
  red1[t] = s1;
  red2[t] = s2;
  __syncthreads();
  if (t < 64) {
    float a1 = red1[t * 4] + red1[t * 4 + 1] + red1[t * 4 + 2] + red1[t * 4 + 3];
    float a2 = red2[t * 4] + red2[t * 4 + 1] + red2[t * 4 + 2] + red2[t * 4 + 3];
    SP[(size_t)blkid * 64 + t] = a1;
    SP[16384 + (size_t)blkid * 64 + t] = a2;
  }
}

// ---------------------------------------------------------------------------
// Kernel 4: normalize + residual with per-block final stats (R12-verified).
// ---------------------------------------------------------------------------
__global__ __launch_bounds__(256) void norm_kernel(
    const float* __restrict__ SP, const float* __restrict__ gamma,
    const float* __restrict__ beta, const float* __restrict__ WY,
    const float* __restrict__ xthis, float* __restrict__ out) {
  __shared__ double rd1[256], rd2[256];
  __shared__ float abr[128];
  __shared__ float xl[64 * 65];
  int b = blockIdx.y, n0 = blockIdx.x * 64, t = threadIdx.x;

  {
    int cc = t & 63, part = t >> 6;
    double d1 = 0.0, d2 = 0.0;
    for (int k = part * 64; k < part * 64 + 64; k++) {
      d1 += (double)SP[(size_t)k * 64 + cc];
      d2 += (double)SP[16384 + (size_t)k * 64 + cc];
    }
    rd1[t] = d1;
    rd2[t] = d2;
  }
#pragma unroll
  for (int it = 0; it < 16; it++) {
    int lin = it * 256 + t;
    int c = lin & 63, dn = lin >> 6;
    xl[dn * 65 + c] = xthis[((size_t)(n0 + dn) * BB + b) * CC + c];
  }
  __syncthreads();
  if (t < 64) {
    double a1 = rd1[t] + rd1[64 + t] + rd1[128 + t] + rd1[192 + t];
    double a2 = rd2[t] + rd2[64 + t] + rd2[128 + t] + rd2[192 + t];
    double inv = 1.0 / (double)(BB * NN);
    double mean = a1 * inv;
    double var = a2 * inv - mean * mean;
    if (var < 0.0) var = 0.0;
    double rstd = 1.0 / sqrt(var + 1e-5);
    float A = gamma[t] * (float)rstd;
    abr[t] = A;
    abr[64 + t] = beta[t] - (float)mean * A;
  }
  __syncthreads();
#pragma unroll
  for (int it = 0; it < 16; it++) {
    int lin = it * 256 + t;
    int c = lin >> 6, dn = lin & 63;
    size_t idx = ((size_t)(b * CC + c)) * NN + n0 + dn;
    out[idx] = WY[idx] * abr[c] + abr[64 + c] + xl[dn * 65 + c];
  }
}

// ---------------------------------------------------------------------------
extern "C" void kernel_launch(void* const* d_in, const int* in_sizes, int n_in,
                              void* d_out, int out_size, void* d_ws,
                              size_t ws_size, hipStream_t stream) {
  const float* x_this = (const float*)d_in[0];
  const float* x_other = (const float*)d_in[1];
  const float* g_w = (const float*)d_in[2];
  const float* g_b = (const float*)d_in[3];
  const float* th_w = (const float*)d_in[4];
  const float* th_b = (const float*)d_in[5];
  const float* ph_w = (const float*)d_in[6];
  const float* ph_b = (const float*)d_in[7];
  const float* wz_w = (const float*)d_in[8];
  const float* wz_b = (const float*)d_in[9];
  const float* gamma = (const float*)d_in[10];
  const float* beta = (const float*)d_in[11];
  float* out = (float*)d_out;

  float* ws = (float*)d_ws;
  ushort_t* Qb = (ushort_t*)(ws + OFF_QB);
  ushort_t* Kb = (ushort_t*)(ws + OFF_KB);
  ushort_t* Vt = (ushort_t*)(ws + OFF_VT);

  int splits = 8;
  while (splits > 1 &&
         ws_size < (size_t)(786432 + (size_t)splits * 540672 + 32768 +
                            1048576) * 4)
    splits >>= 1;
  float* OP = ws + OFF_OP;
  float* LS = OP + (size_t)splits * 524288;
  float* SP = LS + (size_t)splits * 16384;
  float* WY = SP + 32768;

  hipLaunchKernelGGL(proj_kernel, dim3(NN / 64, BB, 3), dim3(256), 0, stream,
                     x_this, x_other, g_w, g_b, th_w, th_b, ph_w, ph_b,
                     Qb, Kb, Vt);
  hipLaunchKernelGGL(attn_kernel, dim3(NN / 256, splits, BB), dim3(256), 0,
                     stream, Qb, Kb, Vt, OP, LS, splits);
  hipLaunchKernelGGL(wz_kernel, dim3(NN / 64, BB), dim3(256), 0, stream,
                     OP, LS, wz_w, wz_b, WY, SP, splits);
  hipLaunchKernelGGL(norm_kernel, dim3(NN / 64, BB), dim3(256), 0, stream,
                     SP, gamma, beta, WY, x_this, out);
}

// Round 14
// 155.689 us; speedup vs baseline: 1.1257x; 1.0281x over previous
//
#include <hip/hip_runtime.h>
#include <hip/hip_bf16.h>
#include <math.h>

typedef unsigned short ushort_t;
typedef __attribute__((ext_vector_type(8))) short short8;
typedef __attribute__((ext_vector_type(4))) float float4v;
typedef __attribute__((ext_vector_type(16))) float float16v;

#define NN 4096
#define BB 4
#define CC 64
#define ICH 32

#define OFF_QB 0
#define OFF_KB 262144
#define OFF_VT 524288
#define OFF_OP 786432

static __device__ __forceinline__ ushort_t f2b(float f) {
  union { float f; unsigned u; } v;
  v.f = f;
  return (ushort_t)((v.u + 0x8000u) >> 16);
}
static __device__ __forceinline__ unsigned pack2(float x, float y) {
  return (unsigned)f2b(x) | ((unsigned)f2b(y) << 16);
}
static __device__ __forceinline__ short8 cvt8lds(const float* p) {
  short8 r;
#pragma unroll
  for (int j = 0; j < 8; j++) r[j] = (short)f2b(p[j]);
  return r;
}

// ---------------------------------------------------------------------------
// Kernel 1: projections via MFMA, one projection per blockIdx.z (R11-proven).
// ---------------------------------------------------------------------------
__global__ __launch_bounds__(256) void proj_kernel(
    const float* __restrict__ xt, const float* __restrict__ xo,
    const float* __restrict__ gw, const float* __restrict__ gb,
    const float* __restrict__ tw, const float* __restrict__ tb,
    const float* __restrict__ pw, const float* __restrict__ pb,
    ushort_t* __restrict__ Qb, ushort_t* __restrict__ Kb,
    ushort_t* __restrict__ Vt) {
  __shared__ float xls[64 * 68];
  __shared__ float wls[ICH * 68];
  __shared__ float bls[ICH];
  __shared__ ushort_t ol[2304];

  int t = threadIdx.x;
  int wv = t >> 6, lane = t & 63, l15 = lane & 15, quad = lane >> 4;
  int b = blockIdx.y, z = blockIdx.z;
  int n0 = blockIdx.x * 64;

  const float* xsrc = (z == 1) ? xo : xt;
  const float* W = (z == 0) ? tw : (z == 1) ? pw : gw;
  const float* Bv = (z == 0) ? tb : (z == 1) ? pb : gb;

#pragma unroll
  for (int it = 0; it < 4; it++) {
    int lin = it * 256 + t;
    int row = lin >> 4, seg = lin & 15;
    float4 v = *(const float4*)(xsrc + ((size_t)(n0 + row) * BB + b) * CC + seg * 4);
    *(float4*)(xls + row * 68 + seg * 4) = v;
  }
#pragma unroll
  for (int it = 0; it < 2; it++) {
    int lin = it * 256 + t;
    int row = lin >> 4, seg = lin & 15;
    float4 v = *(const float4*)(W + (size_t)row * CC + seg * 4);
    *(float4*)(wls + row * 68 + seg * 4) = v;
  }
  if (t < ICH) bls[t] = Bv[t];
  __syncthreads();

  const float* xr = xls + (wv * 16 + l15) * 68;
  short8 a0 = cvt8lds(xr + quad * 8);
  short8 a1 = cvt8lds(xr + 32 + quad * 8);

#pragma unroll
  for (int h = 0; h < 2; h++) {
    int i = h * 16 + l15;
    short8 b0 = cvt8lds(wls + i * 68 + quad * 8);
    short8 b1 = cvt8lds(wls + i * 68 + 32 + quad * 8);
    float bias = bls[i];
    float4v acc = {bias, bias, bias, bias};
    acc = __builtin_amdgcn_mfma_f32_16x16x32_bf16(a0, b0, acc, 0, 0, 0);
    acc = __builtin_amdgcn_mfma_f32_16x16x32_bf16(a1, b1, acc, 0, 0, 0);
    if (z < 2) {
#pragma unroll
      for (int r = 0; r < 4; r++)
        ol[(wv * 16 + quad * 4 + r) * 36 + i] = f2b(acc[r]);
    } else {
#pragma unroll
      for (int r = 0; r < 4; r++)
        ol[i * 68 + wv * 16 + quad * 4 + r] = f2b(acc[r]);
    }
  }
  __syncthreads();

  if (z < 2) {
    ushort_t* dst = (z == 0) ? Kb : Qb;
    int row = t >> 2, seg = t & 3;
    short8 v;
#pragma unroll
    for (int k = 0; k < 8; k++) v[k] = (short)ol[row * 36 + seg * 8 + k];
    *(short8*)(dst + ((size_t)b * NN + n0 + row) * ICH + seg * 8) = v;
  } else {
    int i = t & 31, seg = t >> 5;
    short8 v;
#pragma unroll
    for (int k = 0; k < 8; k++) v[k] = (short)ol[i * 68 + seg * 8 + k];
    *(short8*)(Vt + (size_t)(b * ICH + i) * NN + n0 + seg * 8) = v;
  }
}

// ---------------------------------------------------------------------------
// Kernel 2: MFMA attention partials on 32x32x16 tiles.
// S^T = MFMA(A=K, B=Q^T): C-layout col=q=lane&31, row=kr=(reg&3)+8*(reg>>2)
// +4*h (h=lane>>5).  exp -> P^T; C->B-operand transform is ONE xor-32 hop
// (4 shfl dwords + 8 selects per 1024 elems).  O^T = MFMA(A=V^T, B=P^T)
// accumulates in C-layout; coalesced stores to OPT[bs][ch][n].
// Unnormalized exp (scores bounded, clamp 60); additive split partials.
// ---------------------------------------------------------------------------
__global__ __launch_bounds__(256) void attn_kernel(
    const ushort_t* __restrict__ Qb, const ushort_t* __restrict__ Kb,
    const ushort_t* __restrict__ Vt, float* __restrict__ OPT,
    float* __restrict__ LS, int splits) {
  int t = threadIdx.x;
  int wv = t >> 6, lane = t & 63;
  int l31 = lane & 31, h = lane >> 5;
  int s = blockIdx.y, b = blockIdx.z;
  int q0 = blockIdx.x * 128 + wv * 32;
  int kspan = NN / splits;
  int mbeg = s * kspan, mend = mbeg + kspan;

  const ushort_t* Kbb = Kb + (size_t)b * NN * ICH;
  const ushort_t* Vtb = Vt + (size_t)b * ICH * NN;

  // Q B-frags (loaded once): B[k=ch][n=q]; lane holds Q[q=l31][ch=h*8+j(+16)]
  const ushort_t* qp = Qb + ((size_t)b * NN + q0 + l31) * ICH + h * 8;
  short8 bq0 = *(const short8*)(qp);
  short8 bq1 = *(const short8*)(qp + 16);

  float16v ot;
#pragma unroll
  for (int r = 0; r < 16; r++) ot[r] = 0.f;
  float lsp = 0.f;

  for (int m0 = mbeg; m0 < mend; m0 += 32) {
    // K A-frags: A[m=kr][k=ch]
    const ushort_t* kp = Kbb + (size_t)(m0 + l31) * ICH + h * 8;
    short8 ka0 = *(const short8*)(kp);
    short8 ka1 = *(const short8*)(kp + 16);
    // V^T A-frags: A[m=ch][k=kr]
    const ushort_t* vp = Vtb + (size_t)l31 * NN + m0 + h * 8;
    short8 va0 = *(const short8*)(vp);
    short8 va1 = *(const short8*)(vp + 16);

    float16v st;
#pragma unroll
    for (int r = 0; r < 16; r++) st[r] = 0.f;
    st = __builtin_amdgcn_mfma_f32_32x32x16_bf16(ka0, bq0, st, 0, 0, 0);
    st = __builtin_amdgcn_mfma_f32_32x32x16_bf16(ka1, bq1, st, 0, 0, 0);

    float p[16];
#pragma unroll
    for (int r = 0; r < 16; r++) {
      p[r] = __expf(fminf(st[r], 60.f));
      lsp += p[r];
    }
    // pack pairs: dw[j] = (p[2j], p[2j+1]); h=0: dw0,1=kr0..3  dw2,3=kr8..11
    //   dw4,5=kr16..19 dw6,7=kr24..27 ; h=1: +4 on each.
    unsigned dw[8];
#pragma unroll
    for (int j = 0; j < 8; j++) dw[j] = pack2(p[2 * j], p[2 * j + 1]);

    // exchange #1 (kr 0..15): h=0 needs partner dw0,dw1(kr4..7);
    //   h=1 needs partner dw2,dw3(kr8..11)
    unsigned send0 = h ? dw[0] : dw[2];
    unsigned send1 = h ? dw[1] : dw[3];
    unsigned r0 = (unsigned)__shfl_xor((int)send0, 32, 64);
    unsigned r1 = (unsigned)__shfl_xor((int)send1, 32, 64);
    union { unsigned u[4]; short8 s8; } b1u;
    b1u.u[0] = h ? r0 : dw[0];
    b1u.u[1] = h ? r1 : dw[1];
    b1u.u[2] = h ? dw[2] : r0;
    b1u.u[3] = h ? dw[3] : r1;
    // exchange #2 (kr 16..31)
    unsigned send2 = h ? dw[4] : dw[6];
    unsigned send3 = h ? dw[5] : dw[7];
    unsigned r2 = (unsigned)__shfl_xor((int)send2, 32, 64);
    unsigned r3 = (unsigned)__shfl_xor((int)send3, 32, 64);
    union { unsigned u[4]; short8 s8; } b2u;
    b2u.u[0] = h ? r2 : dw[4];
    b2u.u[1] = h ? r3 : dw[5];
    b2u.u[2] = h ? dw[6] : r2;
    b2u.u[3] = h ? dw[7] : r3;

    ot = __builtin_amdgcn_mfma_f32_32x32x16_bf16(va0, b1u.s8, ot, 0, 0, 0);
    ot = __builtin_amdgcn_mfma_f32_32x32x16_bf16(va1, b2u.s8, ot, 0, 0, 0);
  }

  // per-q row sum: lanes l and l+32 jointly cover all 32 kr rows
  lsp += __shfl_xor(lsp, 32, 64);

  size_t bs = (size_t)(b * splits + s);
  if (h == 0) LS[bs * NN + q0 + l31] = lsp;
#pragma unroll
  for (int r = 0; r < 16; r++) {
    int ch = (r & 3) + 8 * (r >> 2) + 4 * h;
    OPT[(bs * ICH + ch) * NN + q0 + l31] = ot[r];
  }
}

// ---------------------------------------------------------------------------
// Kernel 3: combine splits + wz + BN stat partials.  Reads transposed
// OPT[bs][i][n] (coalesced rows); register-transpose into yl[dn][i].
// ---------------------------------------------------------------------------
__global__ __launch_bounds__(256) void wz_kernel(
    const float* __restrict__ OPT, const float* __restrict__ LS,
    const float* __restrict__ wz_w, const float* __restrict__ wz_b,
    float* __restrict__ WY, float* __restrict__ SP, int splits) {
  __shared__ float yl[64 * 36];
  __shared__ float lsum[64];
  __shared__ float red1[256], red2[256];

  int b = blockIdx.y, n0 = blockIdx.x * 64, t = threadIdx.x;
  int blkid = b * 64 + blockIdx.x;

  if (t < 64) {
    float ssum = 0.f;
    for (int sp = 0; sp < splits; sp++)
      ssum += LS[(size_t)(b * splits + sp) * NN + n0 + t];
    lsum[t] = ssum;
  }
  __syncthreads();
#pragma unroll
  for (int it = 0; it < 8; it++) {
    int lin = it * 256 + t;
    int i = lin >> 6, dn = lin & 63;
    float sacc = 0.f;
    for (int sp = 0; sp < splits; sp++)
      sacc += OPT[((size_t)(b * splits + sp) * ICH + i) * NN + n0 + dn];
    yl[dn * 36 + i] = sacc / lsum[dn];
  }
  __syncthreads();

  int c = t >> 2, sub = t & 3;
  float4 w4[8];
#pragma unroll
  for (int j = 0; j < 8; j++) w4[j] = ((const float4*)(wz_w + c * ICH))[j];
  float bc = wz_b[c];
  float s1 = 0.f, s2 = 0.f;
#pragma unroll
  for (int d = 0; d < 16; d++) {
    int dn = sub * 16 + d;
    const float4* y4 = (const float4*)(yl + dn * 36);
    float acc = bc;
#pragma unroll
    for (int j = 0; j < 8; j++) {
      float4 y = y4[j];
      acc += w4[j].x * y.x + w4[j].y * y.y + w4[j].z * y.z + w4[j].w * y.w;
    }
    WY[((size_t)(b * CC + c)) * NN + n0 + dn] = acc;
    s1 += acc;
    s2 += acc * acc;
  }
  red1[t] = s1;
  red2[t] = s2;
  __syncthreads();
  if (t < 64) {
    float a1 = red1[t * 4] + red1[t * 4 + 1] + red1[t * 4 + 2] + red1[t * 4 + 3];
    float a2 = red2[t * 4] + red2[t * 4 + 1] + red2[t * 4 + 2] + red2[t * 4 + 3];
    SP[(size_t)blkid * 64 + t] = a1;
    SP[16384 + (size_t)blkid * 64 + t] = a2;
  }
}

// ---------------------------------------------------------------------------
// Kernel 4: normalize + residual with per-block final stats (R12-verified).
// ---------------------------------------------------------------------------
__global__ __launch_bounds__(256) void norm_kernel(
    const float* __restrict__ SP, const float* __restrict__ gamma,
    const float* __restrict__ beta, const float* __restrict__ WY,
    const float* __restrict__ xthis, float* __restrict__ out) {
  __shared__ double rd1[256], rd2[256];
  __shared__ float abr[128];
  __shared__ float xl[64 * 65];
  int b = blockIdx.y, n0 = blockIdx.x * 64, t = threadIdx.x;

  {
    int cc = t & 63, part = t >> 6;
    double d1 = 0.0, d2 = 0.0;
    for (int k = part * 64; k < part * 64 + 64; k++) {
      d1 += (double)SP[(size_t)k * 64 + cc];
      d2 += (double)SP[16384 + (size_t)k * 64 + cc];
    }
    rd1[t] = d1;
    rd2[t] = d2;
  }
#pragma unroll
  for (int it = 0; it < 16; it++) {
    int lin = it * 256 + t;
    int c = lin & 63, dn = lin >> 6;
    xl[dn * 65 + c] = xthis[((size_t)(n0 + dn) * BB + b) * CC + c];
  }
  __syncthreads();
  if (t < 64) {
    double a1 = rd1[t] + rd1[64 + t] + rd1[128 + t] + rd1[192 + t];
    double a2 = rd2[t] + rd2[64 + t] + rd2[128 + t] + rd2[192 + t];
    double inv = 1.0 / (double)(BB * NN);
    double mean = a1 * inv;
    double var = a2 * inv - mean * mean;
    if (var < 0.0) var = 0.0;
    double rstd = 1.0 / sqrt(var + 1e-5);
    float A = gamma[t] * (float)rstd;
    abr[t] = A;
    abr[64 + t] = beta[t] - (float)mean * A;
  }
  __syncthreads();
#pragma unroll
  for (int it = 0; it < 16; it++) {
    int lin = it * 256 + t;
    int c = lin >> 6, dn = lin & 63;
    size_t idx = ((size_t)(b * CC + c)) * NN + n0 + dn;
    out[idx] = WY[idx] * abr[c] + abr[64 + c] + xl[dn * 65 + c];
  }
}

// ---------------------------------------------------------------------------
extern "C" void kernel_launch(void* const* d_in, const int* in_sizes, int n_in,
                              void* d_out, int out_size, void* d_ws,
                              size_t ws_size, hipStream_t stream) {
  const float* x_this = (const float*)d_in[0];
  const float* x_other = (const float*)d_in[1];
  const float* g_w = (const float*)d_in[2];
  const float* g_b = (const float*)d_in[3];
  const float* th_w = (const float*)d_in[4];
  const float* th_b = (const float*)d_in[5];
  const float* ph_w = (const float*)d_in[6];
  const float* ph_b = (const float*)d_in[7];
  const float* wz_w = (const float*)d_in[8];
  const float* wz_b = (const float*)d_in[9];
  const float* gamma = (const float*)d_in[10];
  const float* beta = (const float*)d_in[11];
  float* out = (float*)d_out;

  float* ws = (float*)d_ws;
  ushort_t* Qb = (ushort_t*)(ws + OFF_QB);
  ushort_t* Kb = (ushort_t*)(ws + OFF_KB);
  ushort_t* Vt = (ushort_t*)(ws + OFF_VT);

  int splits = 8;
  while (splits > 1 &&
         ws_size < (size_t)(786432 + (size_t)splits * 540672 + 32768 +
                            1048576) * 4)
    splits >>= 1;
  float* OPT = ws + OFF_OP;
  float* LS = OPT + (size_t)splits * 524288;
  float* SP = LS + (size_t)splits * 16384;
  float* WY = SP + 32768;

  hipLaunchKernelGGL(proj_kernel, dim3(NN / 64, BB, 3), dim3(256), 0, stream,
                     x_this, x_other, g_w, g_b, th_w, th_b, ph_w, ph_b,
                     Qb, Kb, Vt);
  hipLaunchKernelGGL(attn_kernel, dim3(NN / 128, splits, BB), dim3(256), 0,
                     stream, Qb, Kb, Vt, OPT, LS, splits);
  hipLaunchKernelGGL(wz_kernel, dim3(NN / 64, BB), dim3(256), 0, stream,
                     OPT, LS, wz_w, wz_b, WY, SP, splits);
  hipLaunchKernelGGL(norm_kernel, dim3(NN / 64, BB), dim3(256), 0, stream,
                     SP, gamma, beta, WY, x_this, out);
}

// Round 15
// 150.989 us; speedup vs baseline: 1.1608x; 1.0311x over previous
//
#include <hip/hip_runtime.h>
#include <hip/hip_bf16.h>
#include <math.h>

typedef unsigned short ushort_t;
typedef __attribute__((ext_vector_type(8))) short short8;
typedef __attribute__((ext_vector_type(4))) float float4v;
typedef __attribute__((ext_vector_type(16))) float float16v;

#define NN 4096
#define BB 4
#define CC 64
#define ICH 32

#define OFF_QB 0
#define OFF_KB 262144
#define OFF_VT 524288
#define OFF_OP 786432

static __device__ __forceinline__ ushort_t f2b(float f) {
  union { float f; unsigned u; } v;
  v.f = f;
  return (ushort_t)((v.u + 0x8000u) >> 16);
}
static __device__ __forceinline__ unsigned pack2(float x, float y) {
  return (unsigned)f2b(x) | ((unsigned)f2b(y) << 16);
}
static __device__ __forceinline__ short8 cvt8lds(const float* p) {
  short8 r;
#pragma unroll
  for (int j = 0; j < 8; j++) r[j] = (short)f2b(p[j]);
  return r;
}

// ---------------------------------------------------------------------------
// Kernel 1: projections via MFMA, one projection per blockIdx.z (R11-proven).
// ---------------------------------------------------------------------------
__global__ __launch_bounds__(256) void proj_kernel(
    const float* __restrict__ xt, const float* __restrict__ xo,
    const float* __restrict__ gw, const float* __restrict__ gb,
    const float* __restrict__ tw, const float* __restrict__ tb,
    const float* __restrict__ pw, const float* __restrict__ pb,
    ushort_t* __restrict__ Qb, ushort_t* __restrict__ Kb,
    ushort_t* __restrict__ Vt) {
  __shared__ float xls[64 * 68];
  __shared__ float wls[ICH * 68];
  __shared__ float bls[ICH];
  __shared__ ushort_t ol[2304];

  int t = threadIdx.x;
  int wv = t >> 6, lane = t & 63, l15 = lane & 15, quad = lane >> 4;
  int b = blockIdx.y, z = blockIdx.z;
  int n0 = blockIdx.x * 64;

  const float* xsrc = (z == 1) ? xo : xt;
  const float* W = (z == 0) ? tw : (z == 1) ? pw : gw;
  const float* Bv = (z == 0) ? tb : (z == 1) ? pb : gb;

#pragma unroll
  for (int it = 0; it < 4; it++) {
    int lin = it * 256 + t;
    int row = lin >> 4, seg = lin & 15;
    float4 v = *(const float4*)(xsrc + ((size_t)(n0 + row) * BB + b) * CC + seg * 4);
    *(float4*)(xls + row * 68 + seg * 4) = v;
  }
#pragma unroll
  for (int it = 0; it < 2; it++) {
    int lin = it * 256 + t;
    int row = lin >> 4, seg = lin & 15;
    float4 v = *(const float4*)(W + (size_t)row * CC + seg * 4);
    *(float4*)(wls + row * 68 + seg * 4) = v;
  }
  if (t < ICH) bls[t] = Bv[t];
  __syncthreads();

  const float* xr = xls + (wv * 16 + l15) * 68;
  short8 a0 = cvt8lds(xr + quad * 8);
  short8 a1 = cvt8lds(xr + 32 + quad * 8);

#pragma unroll
  for (int h = 0; h < 2; h++) {
    int i = h * 16 + l15;
    short8 b0 = cvt8lds(wls + i * 68 + quad * 8);
    short8 b1 = cvt8lds(wls + i * 68 + 32 + quad * 8);
    float bias = bls[i];
    float4v acc = {bias, bias, bias, bias};
    acc = __builtin_amdgcn_mfma_f32_16x16x32_bf16(a0, b0, acc, 0, 0, 0);
    acc = __builtin_amdgcn_mfma_f32_16x16x32_bf16(a1, b1, acc, 0, 0, 0);
    if (z < 2) {
#pragma unroll
      for (int r = 0; r < 4; r++)
        ol[(wv * 16 + quad * 4 + r) * 36 + i] = f2b(acc[r]);
    } else {
#pragma unroll
      for (int r = 0; r < 4; r++)
        ol[i * 68 + wv * 16 + quad * 4 + r] = f2b(acc[r]);
    }
  }
  __syncthreads();

  if (z < 2) {
    ushort_t* dst = (z == 0) ? Kb : Qb;
    int row = t >> 2, seg = t & 3;
    short8 v;
#pragma unroll
    for (int k = 0; k < 8; k++) v[k] = (short)ol[row * 36 + seg * 8 + k];
    *(short8*)(dst + ((size_t)b * NN + n0 + row) * ICH + seg * 8) = v;
  } else {
    int i = t & 31, seg = t >> 5;
    short8 v;
#pragma unroll
    for (int k = 0; k < 8; k++) v[k] = (short)ol[i * 68 + seg * 8 + k];
    *(short8*)(Vt + (size_t)(b * ICH + i) * NN + n0 + seg * 8) = v;
  }
}

// ---------------------------------------------------------------------------
// Kernel 2: MFMA attention partials, 32x32x16 tiles, TWO Q-fragsets per wave
// (64 q rows) so each K/V load feeds 2x the tiles (restores R11 load
// intensity at half its butterfly VALU).  S^T C-layout: col=q=lane&31,
// row=kr=(reg&3)+8*(reg>>2)+4*h (verified R14).  One xor-32 hop C->B.
// No score clamp (|s|<~10 by construction).  Unnormalized exp; additive
// split partials; O^T stored coalesced to OPT[bs][ch][n].
// ---------------------------------------------------------------------------
__global__ __launch_bounds__(256) void attn_kernel(
    const ushort_t* __restrict__ Qb, const ushort_t* __restrict__ Kb,
    const ushort_t* __restrict__ Vt, float* __restrict__ OPT,
    float* __restrict__ LS, int splits) {
  int t = threadIdx.x;
  int wv = t >> 6, lane = t & 63;
  int l31 = lane & 31, h = lane >> 5;
  int s = blockIdx.y, b = blockIdx.z;
  int q0 = blockIdx.x * 256 + wv * 64;  // wave owns 64 q rows (2 fragsets)
  int kspan = NN / splits;
  int mbeg = s * kspan, mend = mbeg + kspan;

  const ushort_t* Kbb = Kb + (size_t)b * NN * ICH;
  const ushort_t* Vtb = Vt + (size_t)b * ICH * NN;

  // Q B-frags per fragset f (q = q0 + f*32 + l31)
  short8 bq0[2], bq1[2];
#pragma unroll
  for (int f = 0; f < 2; f++) {
    const ushort_t* qp = Qb + ((size_t)b * NN + q0 + f * 32 + l31) * ICH + h * 8;
    bq0[f] = *(const short8*)(qp);
    bq1[f] = *(const short8*)(qp + 16);
  }

  float16v ot[2];
#pragma unroll
  for (int f = 0; f < 2; f++)
#pragma unroll
    for (int r = 0; r < 16; r++) ot[f][r] = 0.f;
  float lsp[2] = {0.f, 0.f};

  for (int m0 = mbeg; m0 < mend; m0 += 32) {
    const ushort_t* kp = Kbb + (size_t)(m0 + l31) * ICH + h * 8;
    short8 ka0 = *(const short8*)(kp);
    short8 ka1 = *(const short8*)(kp + 16);
    const ushort_t* vp = Vtb + (size_t)l31 * NN + m0 + h * 8;
    short8 va0 = *(const short8*)(vp);
    short8 va1 = *(const short8*)(vp + 16);

#pragma unroll
    for (int f = 0; f < 2; f++) {
      float16v st;
#pragma unroll
      for (int r = 0; r < 16; r++) st[r] = 0.f;
      st = __builtin_amdgcn_mfma_f32_32x32x16_bf16(ka0, bq0[f], st, 0, 0, 0);
      st = __builtin_amdgcn_mfma_f32_32x32x16_bf16(ka1, bq1[f], st, 0, 0, 0);

      float p[16];
#pragma unroll
      for (int r = 0; r < 16; r++) {
        p[r] = __expf(st[r]);
        lsp[f] += p[r];
      }
      unsigned dw[8];
#pragma unroll
      for (int j = 0; j < 8; j++) dw[j] = pack2(p[2 * j], p[2 * j + 1]);

      unsigned send0 = h ? dw[0] : dw[2];
      unsigned send1 = h ? dw[1] : dw[3];
      unsigned r0 = (unsigned)__shfl_xor((int)send0, 32, 64);
      unsigned r1 = (unsigned)__shfl_xor((int)send1, 32, 64);
      union { unsigned u[4]; short8 s8; } b1u;
      b1u.u[0] = h ? r0 : dw[0];
      b1u.u[1] = h ? r1 : dw[1];
      b1u.u[2] = h ? dw[2] : r0;
      b1u.u[3] = h ? dw[3] : r1;
      unsigned send2 = h ? dw[4] : dw[6];
      unsigned send3 = h ? dw[5] : dw[7];
      unsigned r2 = (unsigned)__shfl_xor((int)send2, 32, 64);
      unsigned r3 = (unsigned)__shfl_xor((int)send3, 32, 64);
      union { unsigned u[4]; short8 s8; } b2u;
      b2u.u[0] = h ? r2 : dw[4];
      b2u.u[1] = h ? r3 : dw[5];
      b2u.u[2] = h ? dw[6] : r2;
      b2u.u[3] = h ? dw[7] : r3;

      ot[f] = __builtin_amdgcn_mfma_f32_32x32x16_bf16(va0, b1u.s8, ot[f], 0, 0, 0);
      ot[f] = __builtin_amdgcn_mfma_f32_32x32x16_bf16(va1, b2u.s8, ot[f], 0, 0, 0);
    }
  }

  size_t bs = (size_t)(b * splits + s);
#pragma unroll
  for (int f = 0; f < 2; f++) {
    float v = lsp[f];
    v += __shfl_xor(v, 32, 64);
    if (h == 0) LS[bs * NN + q0 + f * 32 + l31] = v;
#pragma unroll
    for (int r = 0; r < 16; r++) {
      int ch = (r & 3) + 8 * (r >> 2) + 4 * h;
      OPT[(bs * ICH + ch) * NN + q0 + f * 32 + l31] = ot[f][r];
    }
  }
}

// ---------------------------------------------------------------------------
// Kernel 3: combine splits + wz + BN stat partials (OPT layout, R14-proven).
// ---------------------------------------------------------------------------
__global__ __launch_bounds__(256) void wz_kernel(
    const float* __restrict__ OPT, const float* __restrict__ LS,
    const float* __restrict__ wz_w, const float* __restrict__ wz_b,
    float* __restrict__ WY, float* __restrict__ SP, int splits) {
  __shared__ float yl[64 * 36];
  __shared__ float lsum[64];
  __shared__ float red1[256], red2[256];

  int b = blockIdx.y, n0 = blockIdx.x * 64, t = threadIdx.x;
  int blkid = b * 64 + blockIdx.x;

  if (t < 64) {
    float ssum = 0.f;
    for (int sp = 0; sp < splits; sp++)
      ssum += LS[(size_t)(b * splits + sp) * NN + n0 + t];
    lsum[t] = ssum;
  }
  __syncthreads();
#pragma unroll
  for (int it = 0; it < 8; it++) {
    int lin = it * 256 + t;
    int i = lin >> 6, dn = lin & 63;
    float sacc = 0.f;
    for (int sp = 0; sp < splits; sp++)
      sacc += OPT[((size_t)(b * splits + sp) * ICH + i) * NN + n0 + dn];
    yl[dn * 36 + i] = sacc / lsum[dn];
  }
  __syncthreads();

  int c = t >> 2, sub = t & 3;
  float4 w4[8];
#pragma unroll
  for (int j = 0; j < 8; j++) w4[j] = ((const float4*)(wz_w + c * ICH))[j];
  float bc = wz_b[c];
  float s1 = 0.f, s2 = 0.f;
#pragma unroll
  for (int d = 0; d < 16; d++) {
    int dn = sub * 16 + d;
    const float4* y4 = (const float4*)(yl + dn * 36);
    float acc = bc;
#pragma unroll
    for (int j = 0; j < 8; j++) {
      float4 y = y4[j];
      acc += w4[j].x * y.x + w4[j].y * y.y + w4[j].z * y.z + w4[j].w * y.w;
    }
    WY[((size_t)(b * CC + c)) * NN + n0 + dn] = acc;
    s1 += acc;
    s2 += acc * acc;
  }
  red1[t] = s1;
  red2[t] = s2;
  __syncthreads();
  if (t < 64) {
    float a1 = red1[t * 4] + red1[t * 4 + 1] + red1[t * 4 + 2] + red1[t * 4 + 3];
    float a2 = red2[t * 4] + red2[t * 4 + 1] + red2[t * 4 + 2] + red2[t * 4 + 3];
    SP[(size_t)blkid * 64 + t] = a1;
    SP[16384 + (size_t)blkid * 64 + t] = a2;
  }
}

// ---------------------------------------------------------------------------
// Kernel 4: normalize + residual with per-block final stats (R12-verified).
// ---------------------------------------------------------------------------
__global__ __launch_bounds__(256) void norm_kernel(
    const float* __restrict__ SP, const float* __restrict__ gamma,
    const float* __restrict__ beta, const float* __restrict__ WY,
    const float* __restrict__ xthis, float* __restrict__ out) {
  __shared__ double rd1[256], rd2[256];
  __shared__ float abr[128];
  __shared__ float xl[64 * 65];
  int b = blockIdx.y, n0 = blockIdx.x * 64, t = threadIdx.x;

  {
    int cc = t & 63, part = t >> 6;
    double d1 = 0.0, d2 = 0.0;
    for (int k = part * 64; k < part * 64 + 64; k++) {
      d1 += (double)SP[(size_t)k * 64 + cc];
      d2 += (double)SP[16384 + (size_t)k * 64 + cc];
    }
    rd1[t] = d1;
    rd2[t] = d2;
  }
#pragma unroll
  for (int it = 0; it < 16; it++) {
    int lin = it * 256 + t;
    int c = lin & 63, dn = lin >> 6;
    xl[dn * 65 + c] = xthis[((size_t)(n0 + dn) * BB + b) * CC + c];
  }
  __syncthreads();
  if (t < 64) {
    double a1 = rd1[t] + rd1[64 + t] + rd1[128 + t] + rd1[192 + t];
    double a2 = rd2[t] + rd2[64 + t] + rd2[128 + t] + rd2[192 + t];
    double inv = 1.0 / (double)(BB * NN);
    double mean = a1 * inv;
    double var = a2 * inv - mean * mean;
    if (var < 0.0) var = 0.0;
    double rstd = 1.0 / sqrt(var + 1e-5);
    float A = gamma[t] * (float)rstd;
    abr[t] = A;
    abr[64 + t] = beta[t] - (float)mean * A;
  }
  __syncthreads();
#pragma unroll
  for (int it = 0; it < 16; it++) {
    int lin = it * 256 + t;
    int c = lin >> 6, dn = lin & 63;
    size_t idx = ((size_t)(b * CC + c)) * NN + n0 + dn;
    out[idx] = WY[idx] * abr[c] + abr[64 + c] + xl[dn * 65 + c];
  }
}

// ---------------------------------------------------------------------------
extern "C" void kernel_launch(void* const* d_in, const int* in_sizes, int n_in,
                              void* d_out, int out_size, void* d_ws,
                              size_t ws_size, hipStream_t stream) {
  const float* x_this = (const float*)d_in[0];
  const float* x_other = (const float*)d_in[1];
  const float* g_w = (const float*)d_in[2];
  const float* g_b = (const float*)d_in[3];
  const float* th_w = (const float*)d_in[4];
  const float* th_b = (const float*)d_in[5];
  const float* ph_w = (const float*)d_in[6];
  const float* ph_b = (const float*)d_in[7];
  const float* wz_w = (const float*)d_in[8];
  const float* wz_b = (const float*)d_in[9];
  const float* gamma = (const float*)d_in[10];
  const float* beta = (const float*)d_in[11];
  float* out = (float*)d_out;

  float* ws = (float*)d_ws;
  ushort_t* Qb = (ushort_t*)(ws + OFF_QB);
  ushort_t* Kb = (ushort_t*)(ws + OFF_KB);
  ushort_t* Vt = (ushort_t*)(ws + OFF_VT);

  int splits = 8;
  while (splits > 1 &&
         ws_size < (size_t)(786432 + (size_t)splits * 540672 + 32768 +
                            1048576) * 4)
    splits >>= 1;
  float* OPT = ws + OFF_OP;
  float* LS = OPT + (size_t)splits * 524288;
  float* SP = LS + (size_t)splits * 16384;
  float* WY = SP + 32768;

  hipLaunchKernelGGL(proj_kernel, dim3(NN / 64, BB, 3), dim3(256), 0, stream,
                     x_this, x_other, g_w, g_b, th_w, th_b, ph_w, ph_b,
                     Qb, Kb, Vt);
  hipLaunchKernelGGL(attn_kernel, dim3(NN / 256, splits, BB), dim3(256), 0,
                     stream, Qb, Kb, Vt, OPT, LS, splits);
  hipLaunchKernelGGL(wz_kernel, dim3(NN / 64, BB), dim3(256), 0, stream,
                     OPT, LS, wz_w, wz_b, WY, SP, splits);
  hipLaunchKernelGGL(norm_kernel, dim3(NN / 64, BB), dim3(256), 0, stream,
                     SP, gamma, beta, WY, x_this, out);
}

// Round 16
// 131.525 us; speedup vs baseline: 1.3326x; 1.1480x over previous
//
#include <hip/hip_runtime.h>
#include <hip/hip_bf16.h>
#include <math.h>

typedef unsigned short ushort_t;
typedef __attribute__((ext_vector_type(8))) short short8;
typedef __attribute__((ext_vector_type(4))) float float4v;
typedef __attribute__((ext_vector_type(16))) float float16v;

#define NN 4096
#define BB 4
#define CC 64
#define ICH 32
#define KSPAN 512  // per-wave split span (8 waves/block)

// workspace (float offsets): QB/KB/VT bf16 + WY + SP = ~7.5 MB
#define OFF_QB 0
#define OFF_KB 262144
#define OFF_VT 524288
#define OFF_WY 786432
#define OFF_SP 1835008

static __device__ __forceinline__ ushort_t f2b(float f) {
  union { float f; unsigned u; } v;
  v.f = f;
  return (ushort_t)((v.u + 0x8000u) >> 16);
}
static __device__ __forceinline__ unsigned pack2(float x, float y) {
  return (unsigned)f2b(x) | ((unsigned)f2b(y) << 16);
}
static __device__ __forceinline__ short8 cvt8lds(const float* p) {
  short8 r;
#pragma unroll
  for (int j = 0; j < 8; j++) r[j] = (short)f2b(p[j]);
  return r;
}

// ---------------------------------------------------------------------------
// Kernel 1: projections via MFMA, one projection per blockIdx.z (proven).
// ---------------------------------------------------------------------------
__global__ __launch_bounds__(256) void proj_kernel(
    const float* __restrict__ xt, const float* __restrict__ xo,
    const float* __restrict__ gw, const float* __restrict__ gb,
    const float* __restrict__ tw, const float* __restrict__ tb,
    const float* __restrict__ pw, const float* __restrict__ pb,
    ushort_t* __restrict__ Qb, ushort_t* __restrict__ Kb,
    ushort_t* __restrict__ Vt) {
  __shared__ float xls[64 * 68];
  __shared__ float wls[ICH * 68];
  __shared__ float bls[ICH];
  __shared__ ushort_t ol[2304];

  int t = threadIdx.x;
  int wv = t >> 6, lane = t & 63, l15 = lane & 15, quad = lane >> 4;
  int b = blockIdx.y, z = blockIdx.z;
  int n0 = blockIdx.x * 64;

  const float* xsrc = (z == 1) ? xo : xt;
  const float* W = (z == 0) ? tw : (z == 1) ? pw : gw;
  const float* Bv = (z == 0) ? tb : (z == 1) ? pb : gb;

#pragma unroll
  for (int it = 0; it < 4; it++) {
    int lin = it * 256 + t;
    int row = lin >> 4, seg = lin & 15;
    float4 v = *(const float4*)(xsrc + ((size_t)(n0 + row) * BB + b) * CC + seg * 4);
    *(float4*)(xls + row * 68 + seg * 4) = v;
  }
#pragma unroll
  for (int it = 0; it < 2; it++) {
    int lin = it * 256 + t;
    int row = lin >> 4, seg = lin & 15;
    float4 v = *(const float4*)(W + (size_t)row * CC + seg * 4);
    *(float4*)(wls + row * 68 + seg * 4) = v;
  }
  if (t < ICH) bls[t] = Bv[t];
  __syncthreads();

  const float* xr = xls + (wv * 16 + l15) * 68;
  short8 a0 = cvt8lds(xr + quad * 8);
  short8 a1 = cvt8lds(xr + 32 + quad * 8);

#pragma unroll
  for (int h = 0; h < 2; h++) {
    int i = h * 16 + l15;
    short8 b0 = cvt8lds(wls + i * 68 + quad * 8);
    short8 b1 = cvt8lds(wls + i * 68 + 32 + quad * 8);
    float bias = bls[i];
    float4v acc = {bias, bias, bias, bias};
    acc = __builtin_amdgcn_mfma_f32_16x16x32_bf16(a0, b0, acc, 0, 0, 0);
    acc = __builtin_amdgcn_mfma_f32_16x16x32_bf16(a1, b1, acc, 0, 0, 0);
    if (z < 2) {
#pragma unroll
      for (int r = 0; r < 4; r++)
        ol[(wv * 16 + quad * 4 + r) * 36 + i] = f2b(acc[r]);
    } else {
#pragma unroll
      for (int r = 0; r < 4; r++)
        ol[i * 68 + wv * 16 + quad * 4 + r] = f2b(acc[r]);
    }
  }
  __syncthreads();

  if (z < 2) {
    ushort_t* dst = (z == 0) ? Kb : Qb;
    int row = t >> 2, seg = t & 3;
    short8 v;
#pragma unroll
    for (int k = 0; k < 8; k++) v[k] = (short)ol[row * 36 + seg * 8 + k];
    *(short8*)(dst + ((size_t)b * NN + n0 + row) * ICH + seg * 8) = v;
  } else {
    int i = t & 31, seg = t >> 5;
    short8 v;
#pragma unroll
    for (int k = 0; k < 8; k++) v[k] = (short)ol[i * 68 + seg * 8 + k];
    *(short8*)(Vt + (size_t)(b * ICH + i) * NN + n0 + seg * 8) = v;
  }
}

// ---------------------------------------------------------------------------
// Kernel 2 (fused): attention + split-combine + wz + BN stat partials.
// Block = 512 thr = 8 waves; wave w = split w (static KSPAN=512, 16 chunks).
// Main loop = R15's verified 32x32 2-fragset machinery.  Partials combined
// through LDS (two fixed rounds -> deterministic), normalized into yl, then
// the block does wz projection + SP partials directly.  No OP/LS/Y globals.
// ---------------------------------------------------------------------------
__global__ __launch_bounds__(512) void attn_kernel(
    const ushort_t* __restrict__ Qb, const ushort_t* __restrict__ Kb,
    const ushort_t* __restrict__ Vt, const float* __restrict__ wz_w,
    const float* __restrict__ wz_b, float* __restrict__ WY,
    float* __restrict__ SP) {
  __shared__ float pot[4][ICH][72];  // partial O^T, 4 buffers (2-round comb.)
  __shared__ float pls[8][64];       // per-wave row-sum partials
  __shared__ float wzl[CC * ICH];
  __shared__ float bls[CC];
  __shared__ float yl[64 * 36];      // y tile [dn][i]
  __shared__ float lsum[64];

  int t = threadIdx.x;
  int w = t >> 6, lane = t & 63;
  int l31 = lane & 31, h = lane >> 5;
  int b = blockIdx.y;
  int q0 = blockIdx.x * 64;
  int blkid = b * 64 + blockIdx.x;

  for (int l = t; l < CC * ICH; l += 512) wzl[l] = wz_w[l];
  if (t < CC) bls[t] = wz_b[t];

  const ushort_t* Kbb = Kb + (size_t)b * NN * ICH;
  const ushort_t* Vtb = Vt + (size_t)b * ICH * NN;
  int mbeg = w * KSPAN;

  short8 bq0[2], bq1[2];
#pragma unroll
  for (int f = 0; f < 2; f++) {
    const ushort_t* qp = Qb + ((size_t)b * NN + q0 + f * 32 + l31) * ICH + h * 8;
    bq0[f] = *(const short8*)(qp);
    bq1[f] = *(const short8*)(qp + 16);
  }

  float16v ot[2];
#pragma unroll
  for (int f = 0; f < 2; f++)
#pragma unroll
    for (int r = 0; r < 16; r++) ot[f][r] = 0.f;
  float lsp[2] = {0.f, 0.f};

#pragma unroll 2
  for (int c = 0; c < KSPAN / 32; c++) {
    int m0 = mbeg + c * 32;
    const ushort_t* kp = Kbb + (size_t)(m0 + l31) * ICH + h * 8;
    short8 ka0 = *(const short8*)(kp);
    short8 ka1 = *(const short8*)(kp + 16);
    const ushort_t* vp = Vtb + (size_t)l31 * NN + m0 + h * 8;
    short8 va0 = *(const short8*)(vp);
    short8 va1 = *(const short8*)(vp + 16);

#pragma unroll
    for (int f = 0; f < 2; f++) {
      float16v st;
#pragma unroll
      for (int r = 0; r < 16; r++) st[r] = 0.f;
      st = __builtin_amdgcn_mfma_f32_32x32x16_bf16(ka0, bq0[f], st, 0, 0, 0);
      st = __builtin_amdgcn_mfma_f32_32x32x16_bf16(ka1, bq1[f], st, 0, 0, 0);

      float p[16];
#pragma unroll
      for (int r = 0; r < 16; r++) {
        p[r] = __expf(st[r]);
        lsp[f] += p[r];
      }
      unsigned dw[8];
#pragma unroll
      for (int j = 0; j < 8; j++) dw[j] = pack2(p[2 * j], p[2 * j + 1]);

      unsigned send0 = h ? dw[0] : dw[2];
      unsigned send1 = h ? dw[1] : dw[3];
      unsigned r0 = (unsigned)__shfl_xor((int)send0, 32, 64);
      unsigned r1 = (unsigned)__shfl_xor((int)send1, 32, 64);
      union { unsigned u[4]; short8 s8; } b1u;
      b1u.u[0] = h ? r0 : dw[0];
      b1u.u[1] = h ? r1 : dw[1];
      b1u.u[2] = h ? dw[2] : r0;
      b1u.u[3] = h ? dw[3] : r1;
      unsigned send2 = h ? dw[4] : dw[6];
      unsigned send3 = h ? dw[5] : dw[7];
      unsigned r2 = (unsigned)__shfl_xor((int)send2, 32, 64);
      unsigned r3 = (unsigned)__shfl_xor((int)send3, 32, 64);
      union { unsigned u[4]; short8 s8; } b2u;
      b2u.u[0] = h ? r2 : dw[4];
      b2u.u[1] = h ? r3 : dw[5];
      b2u.u[2] = h ? dw[6] : r2;
      b2u.u[3] = h ? dw[7] : r3;

      ot[f] = __builtin_amdgcn_mfma_f32_32x32x16_bf16(va0, b1u.s8, ot[f], 0, 0, 0);
      ot[f] = __builtin_amdgcn_mfma_f32_32x32x16_bf16(va1, b2u.s8, ot[f], 0, 0, 0);
    }
  }

  // per-q row sums (lanes l and l+32 cover complementary kr halves)
  float lv[2];
#pragma unroll
  for (int f = 0; f < 2; f++) {
    float v = lsp[f];
    v += __shfl_xor(v, 32, 64);
    lv[f] = v;
  }

  // two-round deterministic combine into pot[0..3]
  if (w < 4) {
#pragma unroll
    for (int f = 0; f < 2; f++)
#pragma unroll
      for (int r = 0; r < 16; r++) {
        int ch = (r & 3) + 8 * (r >> 2) + 4 * h;
        pot[w][ch][f * 32 + l31] = ot[f][r];
      }
  }
  if (h == 0) {
#pragma unroll
    for (int f = 0; f < 2; f++) pls[w][f * 32 + l31] = lv[f];
  }
  __syncthreads();
  if (w >= 4) {
#pragma unroll
    for (int f = 0; f < 2; f++)
#pragma unroll
      for (int r = 0; r < 16; r++) {
        int ch = (r & 3) + 8 * (r >> 2) + 4 * h;
        pot[w - 4][ch][f * 32 + l31] += ot[f][r];
      }
  }
  __syncthreads();

  if (t < 64) {
    float s = 0.f;
#pragma unroll
    for (int ww = 0; ww < 8; ww++) s += pls[ww][t];
    lsum[t] = s;
  }
  __syncthreads();

  // normalize into yl[dn][i]
#pragma unroll
  for (int k = 0; k < 4; k++) {
    int lin = k * 512 + t;  // 2048 = 32 i x 64 dn
    int i = lin >> 6, dn = lin & 63;
    float sacc = pot[0][i][dn] + pot[1][i][dn] + pot[2][i][dn] + pot[3][i][dn];
    yl[dn * 36 + i] = sacc / lsum[dn];
  }
  __syncthreads();

  // wz projection + SP partials.  thread -> (c = t>>3, sub = t&7), 8 n each.
  int c = t >> 3, sub = t & 7;
  float4 w4[8];
#pragma unroll
  for (int j = 0; j < 8; j++) w4[j] = ((const float4*)(wzl + c * ICH))[j];
  float bc = bls[c];
  float s1 = 0.f, s2 = 0.f;
#pragma unroll
  for (int d = 0; d < 8; d++) {
    int dn = sub * 8 + d;
    const float4* y4 = (const float4*)(yl + dn * 36);
    float acc = bc;
#pragma unroll
    for (int j = 0; j < 8; j++) {
      float4 y = y4[j];
      acc += w4[j].x * y.x + w4[j].y * y.y + w4[j].z * y.z + w4[j].w * y.w;
    }
    WY[((size_t)(b * CC + c)) * NN + q0 + dn] = acc;
    s1 += acc;
    s2 += acc * acc;
  }
  // reduce over the 8 sub-threads of this c (lanes t^1,2,4 within wave)
  s1 += __shfl_xor(s1, 1, 64);
  s2 += __shfl_xor(s2, 1, 64);
  s1 += __shfl_xor(s1, 2, 64);
  s2 += __shfl_xor(s2, 2, 64);
  s1 += __shfl_xor(s1, 4, 64);
  s2 += __shfl_xor(s2, 4, 64);
  if (sub == 0) {
    SP[(size_t)blkid * 64 + c] = s1;
    SP[16384 + (size_t)blkid * 64 + c] = s2;
  }
}

// ---------------------------------------------------------------------------
// Kernel 3: normalize + residual with per-block final stats (R12-verified).
// ---------------------------------------------------------------------------
__global__ __launch_bounds__(256) void norm_kernel(
    const float* __restrict__ SP, const float* __restrict__ gamma,
    const float* __restrict__ beta, const float* __restrict__ WY,
    const float* __restrict__ xthis, float* __restrict__ out) {
  __shared__ double rd1[256], rd2[256];
  __shared__ float abr[128];
  __shared__ float xl[64 * 65];
  int b = blockIdx.y, n0 = blockIdx.x * 64, t = threadIdx.x;

  {
    int cc = t & 63, part = t >> 6;
    double d1 = 0.0, d2 = 0.0;
    for (int k = part * 64; k < part * 64 + 64; k++) {
      d1 += (double)SP[(size_t)k * 64 + cc];
      d2 += (double)SP[16384 + (size_t)k * 64 + cc];
    }
    rd1[t] = d1;
    rd2[t] = d2;
  }
#pragma unroll
  for (int it = 0; it < 16; it++) {
    int lin = it * 256 + t;
    int c = lin & 63, dn = lin >> 6;
    xl[dn * 65 + c] = xthis[((size_t)(n0 + dn) * BB + b) * CC + c];
  }
  __syncthreads();
  if (t < 64) {
    double a1 = rd1[t] + rd1[64 + t] + rd1[128 + t] + rd1[192 + t];
    double a2 = rd2[t] + rd2[64 + t] + rd2[128 + t] + rd2[192 + t];
    double inv = 1.0 / (double)(BB * NN);
    double mean = a1 * inv;
    double var = a2 * inv - mean * mean;
    if (var < 0.0) var = 0.0;
    double rstd = 1.0 / sqrt(var + 1e-5);
    float A = gamma[t] * (float)rstd;
    abr[t] = A;
    abr[64 + t] = beta[t] - (float)mean * A;
  }
  __syncthreads();
#pragma unroll
  for (int it = 0; it < 16; it++) {
    int lin = it * 256 + t;
    int c = lin >> 6, dn = lin & 63;
    size_t idx = ((size_t)(b * CC + c)) * NN + n0 + dn;
    out[idx] = WY[idx] * abr[c] + abr[64 + c] + xl[dn * 65 + c];
  }
}

// ---------------------------------------------------------------------------
extern "C" void kernel_launch(void* const* d_in, const int* in_sizes, int n_in,
                              void* d_out, int out_size, void* d_ws,
                              size_t ws_size, hipStream_t stream) {
  const float* x_this = (const float*)d_in[0];
  const float* x_other = (const float*)d_in[1];
  const float* g_w = (const float*)d_in[2];
  const float* g_b = (const float*)d_in[3];
  const float* th_w = (const float*)d_in[4];
  const float* th_b = (const float*)d_in[5];
  const float* ph_w = (const float*)d_in[6];
  const float* ph_b = (const float*)d_in[7];
  const float* wz_w = (const float*)d_in[8];
  const float* wz_b = (const float*)d_in[9];
  const float* gamma = (const float*)d_in[10];
  const float* beta = (const float*)d_in[11];
  float* out = (float*)d_out;

  float* ws = (float*)d_ws;
  ushort_t* Qb = (ushort_t*)(ws + OFF_QB);
  ushort_t* Kb = (ushort_t*)(ws + OFF_KB);
  ushort_t* Vt = (ushort_t*)(ws + OFF_VT);
  float* WY = ws + OFF_WY;
  float* SP = ws + OFF_SP;

  hipLaunchKernelGGL(proj_kernel, dim3(NN / 64, BB, 3), dim3(256), 0, stream,
                     x_this, x_other, g_w, g_b, th_w, th_b, ph_w, ph_b,
                     Qb, Kb, Vt);
  hipLaunchKernelGGL(attn_kernel, dim3(NN / 64, BB), dim3(512), 0, stream,
                     Qb, Kb, Vt, wz_w, wz_b, WY, SP);
  hipLaunchKernelGGL(norm_kernel, dim3(NN / 64, BB), dim3(256), 0, stream,
                     SP, gamma, beta, WY, x_this, out);
}